// Round 8
// baseline (53.951 us; speedup 1.0000x reference)
//
#include <hip/hip_runtime.h>
#include <hip/hip_bf16.h>

using f32x4   = __attribute__((ext_vector_type(4))) float;
using bf16x8  = __attribute__((ext_vector_type(8))) short;
using ushort8 = __attribute__((ext_vector_type(8))) unsigned short;

constexpr int N_ = 512;
constexpr int K_ = 512;
constexpr int BM = 128, BN = 128, BK = 64;
constexpr int LDSK = 72;      // 64 + 8 pad
constexpr int NKS = K_ / BK;  // 8

__device__ inline ushort f2bf(float f) {
  union { __hip_bfloat16 h; ushort u; } c;
  c.h = __float2bfloat16(f);
  return c.u;
}

// ---- pre-kernel: pack W[512][512] fp32 -> fragment-linear bf16 (verified r4+) ----
// frag f = n_tile*16 + kc ; lane l holds W[n_tile*16 + (l&15)][kc*32 + (l>>4)*8 ..+8]
__global__ __launch_bounds__(256)
void pack_w(const float* __restrict__ W, ushort* __restrict__ P) {
  const int tau = blockIdx.x * 256 + threadIdx.x;   // 0..32767
  const int l = tau & 63, f = tau >> 6;
  const int row = (f >> 4) * 16 + (l & 15);
  const int kb  = (f & 15) * 32 + (l >> 4) * 8;
  const float* s = W + (size_t)row * K_ + kb;
  f32x4 v0 = *reinterpret_cast<const f32x4*>(s);
  f32x4 v1 = *reinterpret_cast<const f32x4*>(s + 4);
  ushort8 o;
  o[0] = f2bf(v0.x); o[1] = f2bf(v0.y); o[2] = f2bf(v0.z); o[3] = f2bf(v0.w);
  o[4] = f2bf(v1.x); o[5] = f2bf(v1.y); o[6] = f2bf(v1.z); o[7] = f2bf(v1.w);
  *reinterpret_cast<ushort8*>(P + (size_t)tau * 8) = o;
}

// ---- main GEMM: A-only LDS dbuf, B from packed global, counted-wait barriers ----
// The ONLY waits at the barrier are lgkmcnt(0); global loads for ks+1/ks+2 stay
// in flight across it (T4). Compiler inserts precise vmcnt for register uses.
__global__ __launch_bounds__(512, 4)
void gemm_v8(const float* __restrict__ X, const ushort* __restrict__ Wp,
             float* __restrict__ C) {
  __shared__ ushort As[2][BM * LDSK];   // 36 KB

  const int t    = threadIdx.x;
  const int lane = t & 63;
  const int wave = t >> 6;      // 0..7
  const int wr   = wave >> 1;   // 0..3 -> 32-row slab
  const int wc   = wave & 1;    // 0..1 -> 64-col slab

  // XCD-aware bijective swizzle (1024 blocks = 8 XCDs x 128)
  const int cpx = gridDim.x >> 3;
  const int bid = (blockIdx.x & 7) * cpx + (blockIdx.x >> 3);
  const int bn  = bid & 3;
  const int bm  = bid >> 2;
  const int m0 = bm * BM, n0 = bn * BN;

  // A staging map: 512 threads cover 32 rows x 64 cols (f32x4) per slab
  const int sr = t >> 4;        // 0..31
  const int sc = (t & 15) * 4;  // 0,4,...,60

  const float*  xp = X + (size_t)(m0 + sr) * K_ + sc;
  const ushort* bp = Wp + (size_t)((n0 >> 4) + wc * 4) * 16 * 512 + lane * 8;

  f32x4  acc[2][4] = {};
  f32x4  ra[2][4];
  bf16x8 b[8];                  // single-buffered B frags (ni*2 x kk)

  auto LOADA = [&](int set, int ks) {
#pragma unroll
    for (int i = 0; i < 4; ++i)
      ra[set][i] = *reinterpret_cast<const f32x4*>(xp + (size_t)(i * 32) * K_ + ks * BK);
  };

  auto LDB = [&](int ks) {
#pragma unroll
    for (int kk = 0; kk < 2; ++kk)
#pragma unroll
      for (int ni = 0; ni < 4; ++ni)
        b[kk * 4 + ni] = *reinterpret_cast<const bf16x8*>(
            bp + (size_t)(ni * 16 + ks * 2 + kk) * 512);
  };

  auto STAGE = [&](int set, int buf) {   // precise vmcnt wait on ra[set] only
#pragma unroll
    for (int i = 0; i < 4; ++i) {
      ushort4 h;
      h.x = f2bf(ra[set][i].x); h.y = f2bf(ra[set][i].y);
      h.z = f2bf(ra[set][i].z); h.w = f2bf(ra[set][i].w);
      *reinterpret_cast<ushort4*>(&As[buf][(sr + 32 * i) * LDSK + sc]) = h;
    }
  };

  auto MMA = [&](int buf) {
#pragma unroll
    for (int kk = 0; kk < 2; ++kk) {
      const int kof = kk * 32 + (lane >> 4) * 8;
      bf16x8 a0 = *reinterpret_cast<const bf16x8*>(
          &As[buf][(wr * 32 + 0 * 16 + (lane & 15)) * LDSK + kof]);
      bf16x8 a1 = *reinterpret_cast<const bf16x8*>(
          &As[buf][(wr * 32 + 1 * 16 + (lane & 15)) * LDSK + kof]);
      acc[0][0] = __builtin_amdgcn_mfma_f32_16x16x32_bf16(a0, b[kk*4+0], acc[0][0], 0, 0, 0);
      acc[0][1] = __builtin_amdgcn_mfma_f32_16x16x32_bf16(a0, b[kk*4+1], acc[0][1], 0, 0, 0);
      acc[0][2] = __builtin_amdgcn_mfma_f32_16x16x32_bf16(a0, b[kk*4+2], acc[0][2], 0, 0, 0);
      acc[0][3] = __builtin_amdgcn_mfma_f32_16x16x32_bf16(a0, b[kk*4+3], acc[0][3], 0, 0, 0);
      acc[1][0] = __builtin_amdgcn_mfma_f32_16x16x32_bf16(a1, b[kk*4+0], acc[1][0], 0, 0, 0);
      acc[1][1] = __builtin_amdgcn_mfma_f32_16x16x32_bf16(a1, b[kk*4+1], acc[1][1], 0, 0, 0);
      acc[1][2] = __builtin_amdgcn_mfma_f32_16x16x32_bf16(a1, b[kk*4+2], acc[1][2], 0, 0, 0);
      acc[1][3] = __builtin_amdgcn_mfma_f32_16x16x32_bf16(a1, b[kk*4+3], acc[1][3], 0, 0, 0);
    }
  };

  auto SYNC = [&]() {   // ds-visibility only; vmcnt stays outstanding (T4)
    asm volatile("s_waitcnt lgkmcnt(0)" ::: "memory");
    __builtin_amdgcn_s_barrier();
    __builtin_amdgcn_sched_barrier(0);
  };

  // prologue: A(0),A(1) in flight; B(0) in flight; stage A(0)
  LOADA(0, 0);
  LOADA(1, 1);
  LDB(0);
  STAGE(0, 0);
  SYNC();

#pragma unroll
  for (int ks = 0; ks < NKS; ++ks) {
    if (ks + 2 < NKS) LOADA(ks & 1, ks + 2);   // A regs 2-deep, spans barrier
    MMA(ks & 1);                                // consumes b (ks), LDS buf (ks)
    if (ks + 1 < NKS) {
      LDB(ks + 1);                              // refill b after its last use
      STAGE((ks + 1) & 1, (ks + 1) & 1);        // waits only ra[(ks+1)&1]
      SYNC();
    }
  }

  // store: C/D layout col = lane&15, row = (lane>>4)*4 + reg ; nontemporal
  const int col0 = n0 + wc * 64 + (lane & 15);
  const int rsub = (lane >> 4) * 4;
#pragma unroll
  for (int mi = 0; mi < 2; ++mi)
#pragma unroll
    for (int ni = 0; ni < 4; ++ni)
#pragma unroll
      for (int r = 0; r < 4; ++r)
        __builtin_nontemporal_store(
            acc[mi][ni][r],
            &C[(size_t)(m0 + wr * 32 + mi * 16 + rsub + r) * N_ + (col0 + ni * 16)]);
}

// ---- fallback (round-3 kernel) if ws is too small for the W pack ----
constexpr int FBM = 128, FBN = 128, FLDSK = 72, FNKS = 8;

__global__ __launch_bounds__(512, 4)
void gemm_fb(const float* __restrict__ X, const float* __restrict__ W,
             float* __restrict__ C) {
  __shared__ ushort Asf[2][FBM * FLDSK];
  __shared__ ushort Bsf[2][FBN * FLDSK];
  const int t = threadIdx.x, lane = t & 63, wave = t >> 6;
  const int wr = wave >> 2, wc = wave & 3;
  const int cpx = gridDim.x >> 3;
  const int bid = (blockIdx.x & 7) * cpx + (blockIdx.x >> 3);
  const int bn = bid & 3, bm = bid >> 2;
  const int m0 = bm * FBM, n0 = bn * FBN;
  const int sr = t >> 4, sc = (t & 15) * 4;
  const float* xp = X + (size_t)(m0 + sr) * K_ + sc;
  const float* wp = W + (size_t)(n0 + sr) * K_ + sc;
  f32x4 acc[4][2] = {};
  f32x4 ra[2][4], rb[2][4];
  auto LOAD = [&](int set, int ks) {
#pragma unroll
    for (int i = 0; i < 4; ++i) {
      ra[set][i] = *reinterpret_cast<const f32x4*>(xp + (size_t)(i * 32) * K_ + ks * 64);
      rb[set][i] = *reinterpret_cast<const f32x4*>(wp + (size_t)(i * 32) * K_ + ks * 64);
    }
  };
  auto STAGE = [&](int set, int buf) {
#pragma unroll
    for (int i = 0; i < 4; ++i) {
      ushort4 ha, hb;
      ha.x = f2bf(ra[set][i].x); ha.y = f2bf(ra[set][i].y);
      ha.z = f2bf(ra[set][i].z); ha.w = f2bf(ra[set][i].w);
      hb.x = f2bf(rb[set][i].x); hb.y = f2bf(rb[set][i].y);
      hb.z = f2bf(rb[set][i].z); hb.w = f2bf(rb[set][i].w);
      *reinterpret_cast<ushort4*>(&Asf[buf][(sr + 32 * i) * FLDSK + sc]) = ha;
      *reinterpret_cast<ushort4*>(&Bsf[buf][(sr + 32 * i) * FLDSK + sc]) = hb;
    }
  };
  auto MMA = [&](int buf) {
#pragma unroll
    for (int kk = 0; kk < 2; ++kk) {
      const int kof = kk * 32 + (lane >> 4) * 8;
      bf16x8 aa[4], bb[2];
#pragma unroll
      for (int mi = 0; mi < 4; ++mi)
        aa[mi] = *reinterpret_cast<const bf16x8*>(
            &Asf[buf][(wr * 64 + mi * 16 + (lane & 15)) * FLDSK + kof]);
#pragma unroll
      for (int ni = 0; ni < 2; ++ni)
        bb[ni] = *reinterpret_cast<const bf16x8*>(
            &Bsf[buf][(wc * 32 + ni * 16 + (lane & 15)) * FLDSK + kof]);
#pragma unroll
      for (int mi = 0; mi < 4; ++mi)
#pragma unroll
        for (int ni = 0; ni < 2; ++ni)
          acc[mi][ni] = __builtin_amdgcn_mfma_f32_16x16x32_bf16(aa[mi], bb[ni],
                                                                acc[mi][ni], 0, 0, 0);
    }
  };
  LOAD(0, 0); LOAD(1, 1); STAGE(0, 0);
  __syncthreads();
#pragma unroll
  for (int ks = 0; ks < FNKS - 1; ++ks) {
    if (ks + 2 < FNKS) LOAD(ks & 1, ks + 2);
    MMA(ks & 1);
    STAGE((ks + 1) & 1, (ks + 1) & 1);
    __syncthreads();
  }
  MMA((FNKS - 1) & 1);
  const int col0 = n0 + wc * 32 + (lane & 15);
  const int rsub = (lane >> 4) * 4;
#pragma unroll
  for (int mi = 0; mi < 4; ++mi)
#pragma unroll
    for (int ni = 0; ni < 2; ++ni)
#pragma unroll
      for (int r = 0; r < 4; ++r)
        C[(size_t)(m0 + wr * 64 + mi * 16 + rsub + r) * N_ + (col0 + ni * 16)] =
            acc[mi][ni][r];
}

extern "C" void kernel_launch(void* const* d_in, const int* in_sizes, int n_in,
                              void* d_out, int out_size, void* d_ws, size_t ws_size,
                              hipStream_t stream) {
  const float* x = (const float*)d_in[0];
  const float* w = (const float*)d_in[1];
  float* out = (float*)d_out;
  const int M = in_sizes[0] / K_;            // 32768
  dim3 grid((M / BM) * (N_ / BN));           // 1024 blocks
  if (ws_size >= (size_t)(512 * 1024)) {
    ushort* Wp = (ushort*)d_ws;
    pack_w<<<dim3(128), dim3(256), 0, stream>>>(w, Wp);
    gemm_v8<<<grid, dim3(512), 0, stream>>>(x, Wp, out);
  } else {
    gemm_fb<<<grid, dim3(512), 0, stream>>>(x, w, out);
  }
}

// Round 9
// 45.523 us; speedup vs baseline: 1.1851x; 1.1851x over previous
//
#include <hip/hip_runtime.h>
#include <hip/hip_bf16.h>

using f32x4  = __attribute__((ext_vector_type(4))) float;
using bf16x8 = __attribute__((ext_vector_type(8))) short;

constexpr int N_ = 512;
constexpr int K_ = 512;
constexpr int BM = 128, BN = 128, BK = 64;
constexpr int LDSK = 72;      // 64 + 8 pad
constexpr int NKS = K_ / BK;  // 8

__device__ inline ushort f2bf(float f) {
  union { __hip_bfloat16 h; ushort u; } c;
  c.h = __float2bfloat16(f);
  return c.u;
}

// r3 structure (best so far, 37.5us) with ONE change: the per-K-step
// __syncthreads() is replaced by an lgkmcnt-only barrier so the 2-deep
// global register prefetch is NOT drained at the barrier (T4). ds-write
// visibility needs only lgkmcnt(0)+s_barrier; the compiler's counted vmcnt
// waits handle the ra[] register dependencies precisely.
__global__ __launch_bounds__(512, 4)
void gemm_bf16_kernel(const float* __restrict__ X, const float* __restrict__ W,
                      float* __restrict__ C) {
  __shared__ ushort As[2][BM * LDSK];
  __shared__ ushort Bs[2][BN * LDSK];

  const int t    = threadIdx.x;
  const int lane = t & 63;
  const int wave = t >> 6;      // 0..7
  const int wr   = wave >> 2;   // 0..1 -> 64-row slab
  const int wc   = wave & 3;    // 0..3 -> 32-col slab

  // XCD-aware bijective swizzle (1024 blocks = 8 XCDs x 128): the 4 bn-tiles
  // of each x row-panel land on the same XCD -> x re-reads are L2/L3 hits.
  const int cpx = gridDim.x >> 3;
  const int bid = (blockIdx.x & 7) * cpx + (blockIdx.x >> 3);
  const int bn  = bid & 3;
  const int bm  = bid >> 2;
  const int m0 = bm * BM, n0 = bn * BN;

  // staging map: 512 threads cover 32 rows x 64 cols (f32x4) per slab
  const int sr = t >> 4;        // 0..31
  const int sc = (t & 15) * 4;  // 0,4,...,60

  const float* xp = X + (size_t)(m0 + sr) * K_ + sc;
  const float* wp = W + (size_t)(n0 + sr) * K_ + sc;

  f32x4 acc[4][2] = {};
  f32x4 ra[2][4], rb[2][4];

  auto LOAD = [&](int set, int ks) {
#pragma unroll
    for (int i = 0; i < 4; ++i) {
      ra[set][i] = *reinterpret_cast<const f32x4*>(xp + (size_t)(i * 32) * K_ + ks * BK);
      rb[set][i] = *reinterpret_cast<const f32x4*>(wp + (size_t)(i * 32) * K_ + ks * BK);
    }
  };

  auto STAGE = [&](int set, int buf) {   // counted vmcnt wait on ra/rb[set] only
#pragma unroll
    for (int i = 0; i < 4; ++i) {
      ushort4 ha, hb;
      ha.x = f2bf(ra[set][i].x); ha.y = f2bf(ra[set][i].y);
      ha.z = f2bf(ra[set][i].z); ha.w = f2bf(ra[set][i].w);
      hb.x = f2bf(rb[set][i].x); hb.y = f2bf(rb[set][i].y);
      hb.z = f2bf(rb[set][i].z); hb.w = f2bf(rb[set][i].w);
      *reinterpret_cast<ushort4*>(&As[buf][(sr + 32 * i) * LDSK + sc]) = ha;
      *reinterpret_cast<ushort4*>(&Bs[buf][(sr + 32 * i) * LDSK + sc]) = hb;
    }
  };

  auto MMA = [&](int buf) {
#pragma unroll
    for (int kk = 0; kk < 2; ++kk) {
      const int kof = kk * 32 + (lane >> 4) * 8;
      bf16x8 a[4], b[2];
#pragma unroll
      for (int mi = 0; mi < 4; ++mi)
        a[mi] = *reinterpret_cast<const bf16x8*>(
            &As[buf][(wr * 64 + mi * 16 + (lane & 15)) * LDSK + kof]);
#pragma unroll
      for (int ni = 0; ni < 2; ++ni)
        b[ni] = *reinterpret_cast<const bf16x8*>(
            &Bs[buf][(wc * 32 + ni * 16 + (lane & 15)) * LDSK + kof]);
#pragma unroll
      for (int mi = 0; mi < 4; ++mi)
#pragma unroll
        for (int ni = 0; ni < 2; ++ni)
          acc[mi][ni] = __builtin_amdgcn_mfma_f32_16x16x32_bf16(a[mi], b[ni],
                                                                acc[mi][ni], 0, 0, 0);
    }
  };

  auto SYNC = [&]() {  // LDS-visibility barrier; vmcnt prefetch stays in flight
    asm volatile("s_waitcnt lgkmcnt(0)" ::: "memory");
    __builtin_amdgcn_s_barrier();
    __builtin_amdgcn_sched_barrier(0);
  };

  // ---- prologue: loads for ks=0,1 in flight; stage ks=0 into buf0 ----
  LOAD(0, 0);
  LOAD(1, 1);
  STAGE(0, 0);
  SYNC();

  // ---- main loop: 1 barrier per K-step; prefetch spans the barrier ----
#pragma unroll
  for (int ks = 0; ks < NKS - 1; ++ks) {
    if (ks + 2 < NKS) LOAD(ks & 1, ks + 2);   // issue 2 steps ahead
    MMA(ks & 1);                               // compute current
    STAGE((ks + 1) & 1, (ks + 1) & 1);         // waits loads issued 1 iter ago
    SYNC();
  }
  MMA((NKS - 1) & 1);

  // ---- store: C/D layout col = lane&15, row = (lane>>4)*4 + reg ----
  const int col0 = n0 + wc * 32 + (lane & 15);
  const int rsub = (lane >> 4) * 4;
#pragma unroll
  for (int mi = 0; mi < 4; ++mi)
#pragma unroll
    for (int ni = 0; ni < 2; ++ni)
#pragma unroll
      for (int r = 0; r < 4; ++r)
        C[(size_t)(m0 + wr * 64 + mi * 16 + rsub + r) * N_ + (col0 + ni * 16)] =
            acc[mi][ni][r];
}

extern "C" void kernel_launch(void* const* d_in, const int* in_sizes, int n_in,
                              void* d_out, int out_size, void* d_ws, size_t ws_size,
                              hipStream_t stream) {
  const float* x = (const float*)d_in[0];
  const float* w = (const float*)d_in[1];
  float* out = (float*)d_out;
  const int M = in_sizes[0] / K_;            // 32768
  dim3 grid((M / BM) * (N_ / BN));           // 1024 blocks
  gemm_bf16_kernel<<<grid, dim3(512), 0, stream>>>(x, w, out);
}

// Round 10
// 38.292 us; speedup vs baseline: 1.4089x; 1.1888x over previous
//
#include <hip/hip_runtime.h>
#include <hip/hip_bf16.h>

using f32x4  = __attribute__((ext_vector_type(4))) float;
using bf16x8 = __attribute__((ext_vector_type(8))) short;

constexpr int N_ = 512;
constexpr int K_ = 512;
constexpr int BM = 128, BN = 128, BK = 32;
constexpr int LDSK = 36;      // 32 + 4 pad (row stride 72B = 18 dwords -> dense, conflict-free)
constexpr int NKS = K_ / BK;  // 16

__device__ inline ushort f2bf(float f) {
  union { __hip_bfloat16 h; ushort u; } c;
  c.h = __float2bfloat16(f);
  return c.u;
}

// r3 champion schedule (dbuf, 2-deep reg prefetch, 1 __syncthreads/K-step),
// with BK 64->32: LDS 72->36 KB and prefetch regs 64->32, so 3 blocks/CU
// (24 waves/CU) become resident via __launch_bounds__(512,6).
__global__ __launch_bounds__(512, 6)
void gemm_bf16_kernel(const float* __restrict__ X, const float* __restrict__ W,
                      float* __restrict__ C) {
  __shared__ ushort As[2][BM * LDSK];
  __shared__ ushort Bs[2][BN * LDSK];

  const int t    = threadIdx.x;
  const int lane = t & 63;
  const int wave = t >> 6;      // 0..7
  const int wr   = wave >> 2;   // 0..1 -> 64-row slab
  const int wc   = wave & 3;    // 0..3 -> 32-col slab

  // XCD-aware bijective swizzle (1024 blocks = 8 XCDs x 128): the 4 bn-tiles
  // of each x row-panel land on the same XCD -> x re-reads are L2/L3 hits.
  const int cpx = gridDim.x >> 3;
  const int bid = (blockIdx.x & 7) * cpx + (blockIdx.x >> 3);
  const int bn  = bid & 3;
  const int bm  = bid >> 2;
  const int m0 = bm * BM, n0 = bn * BN;

  // staging map: 512 threads cover 64 rows x 32 cols (f32x4) per slab
  const int sr = t >> 3;        // 0..63
  const int sc = (t & 7) * 4;   // 0,4,...,28

  const float* xp = X + (size_t)(m0 + sr) * K_ + sc;
  const float* wp = W + (size_t)(n0 + sr) * K_ + sc;

  f32x4 acc[4][2] = {};
  f32x4 ra[2][2], rb[2][2];     // 2-deep prefetch, 2 f32x4 per matrix per set

  auto LOAD = [&](int set, int ks) {
#pragma unroll
    for (int i = 0; i < 2; ++i) {
      ra[set][i] = *reinterpret_cast<const f32x4*>(xp + (size_t)(i * 64) * K_ + ks * BK);
      rb[set][i] = *reinterpret_cast<const f32x4*>(wp + (size_t)(i * 64) * K_ + ks * BK);
    }
  };

  auto STAGE = [&](int set, int buf) {   // counted vmcnt wait on ra/rb[set] only
#pragma unroll
    for (int i = 0; i < 2; ++i) {
      ushort4 ha, hb;
      ha.x = f2bf(ra[set][i].x); ha.y = f2bf(ra[set][i].y);
      ha.z = f2bf(ra[set][i].z); ha.w = f2bf(ra[set][i].w);
      hb.x = f2bf(rb[set][i].x); hb.y = f2bf(rb[set][i].y);
      hb.z = f2bf(rb[set][i].z); hb.w = f2bf(rb[set][i].w);
      *reinterpret_cast<ushort4*>(&As[buf][(sr + 64 * i) * LDSK + sc]) = ha;
      *reinterpret_cast<ushort4*>(&Bs[buf][(sr + 64 * i) * LDSK + sc]) = hb;
    }
  };

  auto MMA = [&](int buf) {
    const int kof = (lane >> 4) * 8;
    bf16x8 a[4], b[2];
#pragma unroll
    for (int mi = 0; mi < 4; ++mi)
      a[mi] = *reinterpret_cast<const bf16x8*>(
          &As[buf][(wr * 64 + mi * 16 + (lane & 15)) * LDSK + kof]);
#pragma unroll
    for (int ni = 0; ni < 2; ++ni)
      b[ni] = *reinterpret_cast<const bf16x8*>(
          &Bs[buf][(wc * 32 + ni * 16 + (lane & 15)) * LDSK + kof]);
#pragma unroll
    for (int mi = 0; mi < 4; ++mi)
#pragma unroll
      for (int ni = 0; ni < 2; ++ni)
        acc[mi][ni] = __builtin_amdgcn_mfma_f32_16x16x32_bf16(a[mi], b[ni],
                                                              acc[mi][ni], 0, 0, 0);
  };

  // ---- prologue: loads for ks=0,1 in flight; stage ks=0 into buf0 ----
  LOAD(0, 0);
  LOAD(1, 1);
  STAGE(0, 0);
  __syncthreads();

  // ---- main loop: 1 barrier per K-step; 2-deep prefetch ----
#pragma unroll
  for (int ks = 0; ks < NKS - 1; ++ks) {
    if (ks + 2 < NKS) LOAD(ks & 1, ks + 2);   // issue 2 steps ahead
    MMA(ks & 1);                               // compute current
    STAGE((ks + 1) & 1, (ks + 1) & 1);         // waits loads issued 1 iter ago
    __syncthreads();
  }
  MMA((NKS - 1) & 1);

  // ---- store: C/D layout col = lane&15, row = (lane>>4)*4 + reg ----
  const int col0 = n0 + wc * 32 + (lane & 15);
  const int rsub = (lane >> 4) * 4;
#pragma unroll
  for (int mi = 0; mi < 4; ++mi)
#pragma unroll
    for (int ni = 0; ni < 2; ++ni)
#pragma unroll
      for (int r = 0; r < 4; ++r)
        C[(size_t)(m0 + wr * 64 + mi * 16 + rsub + r) * N_ + (col0 + ni * 16)] =
            acc[mi][ni][r];
}

extern "C" void kernel_launch(void* const* d_in, const int* in_sizes, int n_in,
                              void* d_out, int out_size, void* d_ws, size_t ws_size,
                              hipStream_t stream) {
  const float* x = (const float*)d_in[0];
  const float* w = (const float*)d_in[1];
  float* out = (float*)d_out;
  const int M = in_sizes[0] / K_;            // 32768
  dim3 grid((M / BM) * (N_ / BN));           // 1024 blocks
  gemm_bf16_kernel<<<grid, dim3(512), 0, stream>>>(x, w, out);
}